// Round 14
// baseline (612.465 us; speedup 1.0000x reference)
//
#include <hip/hip_runtime.h>
#include <hip/hip_bf16.h>

constexpr int B = 256, S = 1024, T = 64;
constexpr float LOG2E = 1.4426950408889634f;
constexpr float LN2   = 0.6931471805599453f;
constexpr int NSEG = 16;          // segments = waves per block
constexpr int ST   = 66;          // bf16 elems per LDS matrix row (pad vs 64)
constexpr int LDS_BYTES = NSEG * 64 * ST * 2 + NSEG * 4;

typedef short bf16x8 __attribute__((ext_vector_type(8)));
typedef float f32x4  __attribute__((ext_vector_type(4)));

union FragU { unsigned u[4]; unsigned short s[8]; bf16x8 v; };

static __device__ __forceinline__ unsigned cvtpk_bf16(float lo, float hi) {
    unsigned r;
    asm("v_cvt_pk_bf16_f32 %0, %1, %2" : "=v"(r) : "v"(lo), "v"(hi));
    return r;
}
static __device__ __forceinline__ float e2(float x) { return __builtin_amdgcn_exp2f(x); }

// One block per chain; wave w owns segment w (t = 64w+1 .. 64w+64; w=15: ..1023).
// G = Pi (D_t W^T) built as G <- rowscale(W^T G, e^x) with the R11/R13-VERIFIED
// fragment mapping. State lives directly as B-fragment words stB[kt][nt]
// (dword d of stB[kt][nt] = rows 32kt+16(d>>1)+4g+2(d&1)..+1, col 16nt+c).
// Tree combine + finish identical to R13 (absmax 0.0).
__global__ __launch_bounds__(1024, 4) void crf_main(
        const float* __restrict__ emis, const float* __restrict__ U,
        const float* __restrict__ bs,   const float* __restrict__ be,
        const float* __restrict__ peA,  float* __restrict__ nllA) {
    extern __shared__ unsigned short lds_raw[];
    unsigned short* Pm = lds_raw;                          // [NSEG][64*ST] bf16
    float* c2sh = (float*)(lds_raw + NSEG * 64 * ST);      // [NSEG]
    const int chain = blockIdx.x;
    const int tid = threadIdx.x;
    const int w = tid >> 6, l = tid & 63, c = l & 15, g = l >> 4;
    const f32x4 Z4 = {0.f, 0.f, 0.f, 0.f};
    const float* ebase = emis + (size_t)chain * (S * T);
    const float* elane = ebase + 4 * g;                    // per-lane x base

    // ---- A' = W^T fragments (verified mapping) ----
    bf16x8 A[4][2];
#pragma unroll
    for (int mt = 0; mt < 4; ++mt)
#pragma unroll
    for (int kt = 0; kt < 2; ++kt) {
        const int M = 16 * mt + c;
        FragU f;
#pragma unroll
        for (int h = 0; h < 2; ++h) {
            const int Rb = 32 * kt + 16 * h + 4 * g;
            float wv[4];
#pragma unroll
            for (int x = 0; x < 4; ++x)
                wv[x] = e2(U[(Rb + x) * 64 + M] * LOG2E);
            f.u[2 * h]     = cvtpk_bf16(wv[0], wv[1]);
            f.u[2 * h + 1] = cvtpk_bf16(wv[2], wv[3]);
        }
        A[mt][kt] = f.v;
    }

    // ---- init: G = M_{t0} = D_{t0} W^T (B-fragment layout) ----
    const int t0 = 64 * w + 1;
    FragU stB[2][4];
    {
        float Ev0[4][4];
#pragma unroll
        for (int mt = 0; mt < 4; ++mt) {
            float4 xq = *(const float4*)(elane + (size_t)t0 * T + 16 * mt);
            Ev0[mt][0] = xq.x; Ev0[mt][1] = xq.y; Ev0[mt][2] = xq.z; Ev0[mt][3] = xq.w;
        }
#pragma unroll
        for (int nt = 0; nt < 4; ++nt)
#pragma unroll
        for (int mt = 0; mt < 4; ++mt) {
            float4 uq = *(const float4*)(U + (size_t)(16 * nt + c) * 64 + 16 * mt + 4 * g);
            float s0 = e2((Ev0[mt][0] + uq.x) * LOG2E);
            float s1 = e2((Ev0[mt][1] + uq.y) * LOG2E);
            float s2 = e2((Ev0[mt][2] + uq.z) * LOG2E);
            float s3 = e2((Ev0[mt][3] + uq.w) * LOG2E);
            stB[mt >> 1][nt].u[2 * (mt & 1)]     = cvtpk_bf16(s0, s1);
            stB[mt >> 1][nt].u[2 * (mt & 1) + 1] = cvtpk_bf16(s2, s3);
        }
    }
    int c2i = 0;

    // ---- one step: G <- rowscale(W^T G, e^{x_t}), scale folded into exp2 arg ----
    auto dostep = [&](const float4 (&xq)[4], int t) {
        float4 xv[4];
#pragma unroll
        for (int mt = 0; mt < 4; ++mt) xv[mt] = xq[mt];
        if (t == S - 1) {                         // fold b_end once (wave-uniform)
#pragma unroll
            for (int mt = 0; mt < 4; ++mt) {
                float4 bq = *(const float4*)(be + 16 * mt + 4 * g);
                xv[mt].x += bq.x; xv[mt].y += bq.y; xv[mt].z += bq.z; xv[mt].w += bq.w;
            }
        }
        f32x4 Es[4];
#pragma unroll
        for (int nt = 0; nt < 4; ++nt) {
            bf16x8 B0 = stB[0][nt].v;
            bf16x8 B1 = stB[1][nt].v;
            f32x4 acc[4];
#pragma unroll
            for (int mt = 0; mt < 4; ++mt)
                acc[mt] = __builtin_amdgcn_mfma_f32_16x16x32_bf16(A[mt][0], B0, Z4, 0, 0, 0);
#pragma unroll
            for (int mt = 0; mt < 4; ++mt)
                acc[mt] = __builtin_amdgcn_mfma_f32_16x16x32_bf16(A[mt][1], B1, acc[mt], 0, 0, 0);
            if (nt == 0) {
                unsigned rb = __builtin_amdgcn_readfirstlane(__float_as_uint(acc[0][0]));
                int e = (int)((rb >> 23) & 0xFF);
                c2i += e - 127;
                float fsc = (float)(127 - e);     // *2^fsc folded into exp2 arg
#pragma unroll
                for (int mt = 0; mt < 4; ++mt) {
                    Es[mt][0] = e2(__builtin_fmaf(xv[mt].x, LOG2E, fsc));
                    Es[mt][1] = e2(__builtin_fmaf(xv[mt].y, LOG2E, fsc));
                    Es[mt][2] = e2(__builtin_fmaf(xv[mt].z, LOG2E, fsc));
                    Es[mt][3] = e2(__builtin_fmaf(xv[mt].w, LOG2E, fsc));
                }
            }
#pragma unroll
            for (int mt = 0; mt < 4; ++mt) {
                f32x4 pr = acc[mt] * Es[mt];      // vector mul -> v_pk_mul_f32
                stB[mt >> 1][nt].u[2 * (mt & 1)]     = cvtpk_bf16(pr[0], pr[1]);
                stB[mt >> 1][nt].u[2 * (mt & 1) + 1] = cvtpk_bf16(pr[2], pr[3]);
            }
        }
    };

    auto ldx = [&](float4 (&xq)[4], int t) {
        int tc = t < S - 1 ? t : S - 1;
        const float* p = elane + (size_t)tc * T;
#pragma unroll
        for (int mt = 0; mt < 4; ++mt)
            xq[mt] = *(const float4*)(p + 16 * mt);
    };

    // ---- scan: 2-deep ping-pong; w<15: 63 steps, w==15: 62 steps ----
    float4 xa[4], xb[4];
    ldx(xa, t0 + 1); ldx(xb, t0 + 2);
#pragma unroll 1
    for (int k = 0; k < 31; ++k) {
        dostep(xa, t0 + 1 + 2 * k); ldx(xa, t0 + 3 + 2 * k);
        dostep(xb, t0 + 2 + 2 * k); ldx(xb, t0 + 4 + 2 * k);
    }
    if (w < NSEG - 1) dostep(xa, t0 + 63);

    // ---- store segment product to LDS slot w (row-major bf16) ----
    {
        unsigned short* myP = Pm + (size_t)w * (64 * ST);
#pragma unroll
        for (int kt = 0; kt < 2; ++kt)
#pragma unroll
        for (int nt = 0; nt < 4; ++nt)
#pragma unroll
        for (int d = 0; d < 4; ++d) {
            const int row = 32 * kt + 16 * (d >> 1) + 4 * g + 2 * (d & 1);
            const int col = 16 * nt + c;
            unsigned word = stB[kt][nt].u[d];
            myP[row * ST + col]       = (unsigned short)(word & 0xFFFFu);
            myP[(row + 1) * ST + col] = (unsigned short)(word >> 16);
        }
        if (l == 0) c2sh[w] = (float)c2i;
    }

    // ---- tree combine: slot w <- slot(2w+1) x slot(2w) (verbatim R13) ----
    for (int nact = NSEG / 2; nact >= 1; nact >>= 1) {
        __syncthreads();
        unsigned outst[4][4][2];
        float c2n = 0.f;
        if (w < nact) {
            const unsigned short* Gl = Pm + (size_t)(2 * w + 1) * (64 * ST);
            const unsigned short* Gr = Pm + (size_t)(2 * w) * (64 * ST);
            bf16x8 TA[4][2];
#pragma unroll
            for (int mt = 0; mt < 4; ++mt)
#pragma unroll
            for (int kt = 0; kt < 2; ++kt) {
                FragU f;
#pragma unroll
                for (int i = 0; i < 8; ++i)
                    f.s[i] = Gl[(16 * mt + c) * ST + 32 * kt + 16 * (i >> 2) + 4 * g + (i & 3)];
                TA[mt][kt] = f.v;
            }
            float sc = 1.0f;
#pragma unroll
            for (int nt = 0; nt < 4; ++nt) {
                FragU b0, b1;
#pragma unroll
                for (int i = 0; i < 8; ++i) {
                    const int R = 16 * (i >> 2) + 4 * g + (i & 3);
                    b0.s[i] = Gr[R * ST + 16 * nt + c];
                    b1.s[i] = Gr[(32 + R) * ST + 16 * nt + c];
                }
                f32x4 acc[4];
#pragma unroll
                for (int mt = 0; mt < 4; ++mt)
                    acc[mt] = __builtin_amdgcn_mfma_f32_16x16x32_bf16(TA[mt][0], b0.v, Z4, 0, 0, 0);
#pragma unroll
                for (int mt = 0; mt < 4; ++mt)
                    acc[mt] = __builtin_amdgcn_mfma_f32_16x16x32_bf16(TA[mt][1], b1.v, acc[mt], 0, 0, 0);
                if (nt == 0) {
                    unsigned rb = __builtin_amdgcn_readfirstlane(__float_as_uint(acc[0][0]));
                    int e = (int)((rb >> 23) & 0xFF);
                    c2n = c2sh[2 * w] + c2sh[2 * w + 1] + (float)(e - 127);
                    sc = __uint_as_float((unsigned)(254 - e) << 23);
                }
#pragma unroll
                for (int mt = 0; mt < 4; ++mt) {
                    outst[mt][nt][0] = cvtpk_bf16(acc[mt][0] * sc, acc[mt][1] * sc);
                    outst[mt][nt][1] = cvtpk_bf16(acc[mt][2] * sc, acc[mt][3] * sc);
                }
            }
        }
        __syncthreads();
        if (w < nact) {
            unsigned short* Po = Pm + (size_t)w * (64 * ST);
#pragma unroll
            for (int mt = 0; mt < 4; ++mt)
#pragma unroll
            for (int nt = 0; nt < 4; ++nt)
#pragma unroll
            for (int p = 0; p < 2; ++p) {
                const int row = 16 * mt + 4 * g + 2 * p, col = 16 * nt + c;
                Po[row * ST + col]       = (unsigned short)(outst[mt][nt][p] & 0xFFFFu);
                Po[(row + 1) * ST + col] = (unsigned short)(outst[mt][nt][p] >> 16);
            }
            if (l == 0) c2sh[w] = c2n;
        }
    }
    __syncthreads();

    // ---- finish: Z = sum_c (colsum P)[c] * alpha0[c] ----
    if (w == 0) {
        float s = 0.f;
#pragma unroll 8
        for (int r = 0; r < 64; ++r) {
            unsigned u = Pm[r * ST + l];
            s += __uint_as_float(u << 16);
        }
        float a0 = e2((ebase[l] + bs[l]) * LOG2E);
        float z = s * a0;
#pragma unroll
        for (int m = 1; m < 64; m <<= 1) z += __shfl_xor(z, m, 64);
        if (l == 0)
            nllA[chain] = LN2 * (__builtin_amdgcn_logf(z) + c2sh[0]) - peA[chain];
    }
}

// ---- path energy (proven) ----
__global__ __launch_bounds__(64) void crf_pe(
        const float* __restrict__ emis, const int* __restrict__ tags,
        const float* __restrict__ U,    const float* __restrict__ bs,
        const float* __restrict__ be,   float* __restrict__ peArr) {
    const int chain = blockIdx.x, j = threadIdx.x;
    const float* eb = emis + (size_t)chain * (S * T);
    const int*   tb = tags + (size_t)chain * S;
    float pe = 0.f;
#pragma unroll
    for (int sc = 0; sc < 16; ++sc) {
        int s  = sc * 64 + j;
        int tg = tb[s];
        float e = eb[(size_t)s * T + tg];
        if (s == 0)     e += bs[tg];
        if (s == S - 1) e += be[tg];
        pe += e;
        if (s < S - 1)  pe += U[tg * 64 + tb[s + 1]];
    }
#pragma unroll
    for (int m = 1; m < 64; m <<= 1) pe += __shfl_xor(pe, m, 64);
    if (j == 0) peArr[chain] = pe;
}

__global__ __launch_bounds__(256, 1) void crf_reduce(const float* __restrict__ nll,
                                                     float* __restrict__ out) {
    float v = nll[threadIdx.x];
#pragma unroll
    for (int m = 1; m < 64; m <<= 1) v += __shfl_xor(v, m, 64);
    __shared__ float acc[4];
    if ((threadIdx.x & 63) == 0) acc[threadIdx.x >> 6] = v;
    __syncthreads();
    if (threadIdx.x == 0) out[0] = (acc[0] + acc[1] + acc[2] + acc[3]) * (1.0f / B);
}

extern "C" void kernel_launch(void* const* d_in, const int* in_sizes, int n_in,
                              void* d_out, int out_size, void* d_ws, size_t ws_size,
                              hipStream_t stream) {
    const float* emis = (const float*)d_in[0];
    const int*   tags = (const int*)d_in[1];
    const float* U    = (const float*)d_in[2];
    const float* bs   = (const float*)d_in[3];
    const float* be   = (const float*)d_in[4];

    float* ws   = (float*)d_ws;
    float* peA  = ws;            // 256
    float* nllA = ws + 256;      // 256

    (void)hipFuncSetAttribute((const void*)crf_main,
                              hipFuncAttributeMaxDynamicSharedMemorySize, LDS_BYTES);

    crf_pe  <<<dim3(B), dim3(64),   0,         stream>>>(emis, tags, U, bs, be, peA);
    crf_main<<<dim3(B), dim3(1024), LDS_BYTES, stream>>>(emis, U, bs, be, peA, nllA);
    crf_reduce<<<dim3(1), dim3(256), 0,        stream>>>(nllA, (float*)d_out);
}